// Round 2
// baseline (94.954 us; speedup 1.0000x reference)
//
#include <hip/hip_runtime.h>

// SpaceToDepth bs=2: x0 (16,64,256,256) f32 -> y (16,256,128,128) f32, plus x1 (16,) passthrough.
// y[b, h_in*128 + w_in*64 + c, ho, wo] = x0[b, c, 2*ho + h_in, 2*wo + w_in]
// d_out = [ y flat (67,108,864 floats) | x1 (16 floats) ]
//
// R2: 32B per lane (two adjacent input float4s) -> two full float4 stores per lane,
// plus nontemporal load/store (touch-once streams, skip cache pollution).

typedef float v4f __attribute__((ext_vector_type(4)));

constexpr int Bn = 16, Cn = 64, Hn = 256, Wn = 256;
constexpr int HOn = Hn / 2, WOn = Wn / 2;                             // 128, 128
constexpr long long Y_ELEMS = (long long)Bn * (4 * Cn) * HOn * WOn;   // 67,108,864
constexpr long long N_F4 = (long long)Bn * Cn * Hn * Wn / 4;          // 16,777,216 float4 units
constexpr long long WIN1_OFF = (long long)Cn * HOn * WOn;             // 1,048,576 floats (d += 64)

__global__ void __launch_bounds__(256) s2d_kernel(const v4f* __restrict__ in,
                                                  const float* __restrict__ x1,
                                                  float* __restrict__ out) {
    long long t = (long long)blockIdx.x * blockDim.x + threadIdx.x;
    long long p = t << 1;                 // this lane owns input float4s p and p+1

    // input flat float4 index decomposes as (b, c, h, w4) with W4=64, H=256, C=64
    int w4 = (int)(p & 63);               // even (p even), so wo = 2*w4 is a multiple of 4
    int h  = (int)((p >> 6) & 255);
    int c  = (int)((p >> 14) & 63);
    int b  = (int)(p >> 20);

    v4f v0 = __builtin_nontemporal_load(in + p);
    v4f v1 = __builtin_nontemporal_load(in + p + 1);

    int ho  = h >> 1;
    int hin = h & 1;
    int wo  = w4 << 1;                    // multiple of 4 -> 16B-aligned float4 stores

    // w_in = 0 channel: d = hin*128 + c ; w_in = 1 channel: d += 64
    long long base = ((((long long)b * 256 + (long long)(hin * 128 + c)) * HOn) + ho) * WOn + wo;

    v4f s0 = {v0.x, v0.z, v1.x, v1.z};    // w_in = 0 -> wo..wo+3
    v4f s1 = {v0.y, v0.w, v1.y, v1.w};    // w_in = 1 -> wo..wo+3 in channel d+64

    __builtin_nontemporal_store(s0, (v4f*)(out + base));
    __builtin_nontemporal_store(s1, (v4f*)(out + base + WIN1_OFF));

    // x1 passthrough (16 floats) appended after y
    if (blockIdx.x == 0 && threadIdx.x < 16) {
        out[Y_ELEMS + threadIdx.x] = x1[threadIdx.x];
    }
}

extern "C" void kernel_launch(void* const* d_in, const int* in_sizes, int n_in,
                              void* d_out, int out_size, void* d_ws, size_t ws_size,
                              hipStream_t stream) {
    const v4f*   x0 = (const v4f*)d_in[0];
    const float* x1 = (const float*)d_in[1];
    float* out = (float*)d_out;

    const int block = 256;
    const long long grid = (N_F4 / 2) / block;  // 32,768 blocks, exact
    s2d_kernel<<<(int)grid, block, 0, stream>>>(x0, x1, out);
}